// Round 18
// baseline (109.651 us; speedup 1.0000x reference)
//
#include <hip/hip_runtime.h>
#include <hip/hip_bf16.h>

#define NROWS 8192
#define FDIM 128
#define KNN 10
#define K2 11
#define C_CONST 1.0e-3f
#define L_CONST 5.0f
#define EPS_CONST 1.0e-3f
#define BIGF 3.0e38f
#define BCAP 13
#define TRIG 6

typedef float f32x4 __attribute__((ext_vector_type(4)));
typedef float f32x16 __attribute__((ext_vector_type(16)));
typedef __bf16 bf16x8 __attribute__((ext_vector_type(8)));
typedef unsigned short ushort4v __attribute__((ext_vector_type(4)));
typedef unsigned short ushort8v __attribute__((ext_vector_type(8)));

__device__ __forceinline__ unsigned short f32_to_bf16_rne(float f) {
    unsigned int x = __float_as_uint(f);
    unsigned int lsb = (x >> 16) & 1u;
    x += 0x7fffu + lsb;
    return (unsigned short)(x >> 16);
}

__device__ __forceinline__ void split_bf16(float v, unsigned short& h, unsigned short& l) {
    unsigned short hh = f32_to_bf16_rne(v);
    float hf = __uint_as_float(((unsigned int)hh) << 16);
    h = hh;
    l = f32_to_bf16_rne(v - hf);
}

__device__ __forceinline__ void insert11(float* v, float tv) {
    #pragma unroll
    for (int u = 0; u < K2; ++u) {
        float lo = fminf(v[u], tv);
        tv = fmaxf(v[u], tv);
        v[u] = lo;
    }
}

__device__ __forceinline__ void compactB(float* v, const float* bp, int cnt) {
    #pragma unroll
    for (int i = 0; i < BCAP; ++i) {
        float tv = (i < cnt) ? bp[i] : BIGF;
        insert11(v, tv);
    }
}

__device__ __forceinline__ void ce(float& a, float& b) {
    float lo = fminf(a, b), hi = fmaxf(a, b); a = lo; b = hi;
}
__device__ __forceinline__ void sortBitonic11(float* w) {
    ce(w[0],w[8]); ce(w[1],w[9]); ce(w[2],w[10]);
    ce(w[0],w[4]); ce(w[1],w[5]); ce(w[2],w[6]); ce(w[3],w[7]);
    ce(w[0],w[2]); ce(w[1],w[3]); ce(w[4],w[6]); ce(w[5],w[7]); ce(w[8],w[10]);
    ce(w[0],w[1]); ce(w[2],w[3]); ce(w[4],w[5]); ce(w[6],w[7]); ce(w[8],w[9]);
}

// ---------------- K0: prep (s fragment split + weight frag + biases + zero total) ----------------
__global__ __launch_bounds__(256) void k_prepw(
    const float* __restrict__ s,
    const float* __restrict__ w1, const float* __restrict__ wt1, const float* __restrict__ wz1,
    const float* __restrict__ w2, const float* __restrict__ wt2, const float* __restrict__ wz2,
    const float* __restrict__ w3, const float* __restrict__ wt3, const float* __restrict__ wz3,
    const float* __restrict__ b1, const float* __restrict__ bt1, const float* __restrict__ bz1,
    const float* __restrict__ b2, const float* __restrict__ bt2, const float* __restrict__ bz2,
    const float* __restrict__ b3, const float* __restrict__ bt3, const float* __restrict__ bz3,
    unsigned short* __restrict__ sf,
    unsigned short* __restrict__ w1f, unsigned short* __restrict__ w2f,
    unsigned short* __restrict__ w3f,
    float* __restrict__ b1c, float* __restrict__ b2c, float* __restrict__ b3c,
    float* __restrict__ total)
{
    const int b = blockIdx.x;
    const int t = threadIdx.x;
    const int wv = t >> 6, lane = t & 63;
    const int l15 = lane & 15, lg = lane >> 4;

    if (b < 2048) {
        const int w = b * 4 + wv;
        const int mt = w >> 4, kt = w & 15;
        const float* src = s + (size_t)(mt * 16 + l15) * 512 + kt * 32 + lg * 8;
        f32x4 a = *(const f32x4*)src;
        f32x4 c = *(const f32x4*)(src + 4);
        ushort8v h, l;
        #pragma unroll
        for (int j = 0; j < 4; ++j) {
            unsigned short hh, ll;
            split_bf16(a[j], hh, ll); h[j] = hh; l[j] = ll;
            split_bf16(c[j], hh, ll); h[4 + j] = hh; l[4 + j] = ll;
        }
        unsigned short* dst = sf + ((size_t)(mt * 16 + kt) * 64 + lane) * 16;
        *(ushort8v*)dst = h;
        *(ushort8v*)(dst + 8) = l;
    } else if (b < 2144) {
        const int w = (b - 2048) * 4 + wv;
        const int nt = w >> 4, kt = w & 15;
        const int n = nt * 16 + l15, k = kt * 32 + lg * 8;
        const float* src = (n < 128) ? (w1 + (size_t)n * 512 + k)
                         : (n < 256) ? (wt1 + (size_t)(n - 128) * 512 + k)
                                     : (wz1 + (size_t)(n - 256) * 512 + k);
        f32x4 a = *(const f32x4*)src;
        f32x4 c = *(const f32x4*)(src + 4);
        ushort8v h, l;
        #pragma unroll
        for (int j = 0; j < 4; ++j) {
            unsigned short hh, ll;
            split_bf16(a[j], hh, ll); h[j] = hh; l[j] = ll;
            split_bf16(c[j], hh, ll); h[4 + j] = hh; l[4 + j] = ll;
        }
        unsigned short* dst = w1f + ((size_t)(nt * 16 + kt) * 64 + lane) * 16;
        *(ushort8v*)dst = h;
        *(ushort8v*)(dst + 8) = l;
    } else if (b < 2180) {
        const int w = (b - 2144) * 4 + wv;
        const int nt = w / 12, kt = w % 12;
        const int n = nt * 16 + l15, k = kt * 32 + lg * 8;
        f32x4 a = {0.f,0.f,0.f,0.f}, c = {0.f,0.f,0.f,0.f};
        if (n < 64)       { if (k < 128)             { const float* p = w2  + (size_t)n * 128 + k;                 a = *(const f32x4*)p; c = *(const f32x4*)(p + 4); } }
        else if (n < 128) { if (k >= 128 && k < 256) { const float* p = wt2 + (size_t)(n - 64) * 128 + (k - 128);  a = *(const f32x4*)p; c = *(const f32x4*)(p + 4); } }
        else              { if (k >= 256)            { const float* p = wz2 + (size_t)(n - 128) * 128 + (k - 256); a = *(const f32x4*)p; c = *(const f32x4*)(p + 4); } }
        ushort8v h, l;
        #pragma unroll
        for (int j = 0; j < 4; ++j) {
            unsigned short hh, ll;
            split_bf16(a[j], hh, ll); h[j] = hh; l[j] = ll;
            split_bf16(c[j], hh, ll); h[4 + j] = hh; l[4 + j] = ll;
        }
        unsigned short* dst = w2f + ((size_t)(nt * 12 + kt) * 64 + lane) * 16;
        *(ushort8v*)dst = h;
        *(ushort8v*)(dst + 8) = l;
    } else if (b < 2194) {
        const int w = (b - 2180) * 4 + wv;
        if (w < 54) {
            const int nt = w / 6, kt = w % 6;
            const int n = nt * 16 + l15, k = kt * 32 + lg * 8;
            f32x4 a = {0.f,0.f,0.f,0.f}, c = {0.f,0.f,0.f,0.f};
            if (n == 0)                  { if (k < 64)             { const float* p = w3 + k;                                   a = *(const f32x4*)p; c = *(const f32x4*)(p + 4); } }
            else if (n == 1)             { if (k >= 64 && k < 128) { const float* p = wt3 + (k - 64);                           a = *(const f32x4*)p; c = *(const f32x4*)(p + 4); } }
            else if (n >= 16 && n < 144) { if (k >= 128)           { const float* p = wz3 + (size_t)(n - 16) * 64 + (k - 128);  a = *(const f32x4*)p; c = *(const f32x4*)(p + 4); } }
            ushort8v h, l;
            #pragma unroll
            for (int j = 0; j < 4; ++j) {
                unsigned short hh, ll;
                split_bf16(a[j], hh, ll); h[j] = hh; l[j] = ll;
                split_bf16(c[j], hh, ll); h[4 + j] = hh; l[4 + j] = ll;
            }
            unsigned short* dst = w3f + ((size_t)(nt * 6 + kt) * 64 + lane) * 16;
            *(ushort8v*)dst = h;
            *(ushort8v*)(dst + 8) = l;
        }
    } else {
        if (t == 0) *total = 0.f;
        for (int i = t; i < 720; i += 256) {
            if (i < 384)      b1c[i] = (i < 128) ? b1[i] : (i < 256) ? bt1[i - 128] : bz1[i - 256];
            else if (i < 576) { int j = i - 384; b2c[j] = (j < 64) ? b2[j] : (j < 128) ? bt2[j - 64] : bz2[j - 128]; }
            else              { int j = i - 576; b3c[j] = (j == 0) ? b3[0] : (j == 1) ? bt3[0] : (j < 16) ? 0.f : bz3[j - 16]; }
        }
    }
}

// ---------------- K1: fused 3-layer MLP, 2 m-tiles/block; z written in 32-row fragment layout ----------------
__global__ __launch_bounds__(512, 4) void k_mlp(
    const unsigned short* __restrict__ sf,
    const unsigned short* __restrict__ w1f, const unsigned short* __restrict__ w2f,
    const unsigned short* __restrict__ w3f,
    const float* __restrict__ b1c, const float* __restrict__ b2c, const float* __restrict__ b3c,
    unsigned short* __restrict__ zf, float* __restrict__ sq, float* __restrict__ alpha)
{
    __shared__ unsigned short h1frag[2][12][64][16];
    __shared__ unsigned short h2frag[2][6][64][16];
    __shared__ float sred[2][8][16];

    const int t = threadIdx.x;
    const int lane = t & 63, wv = t >> 6;
    const int l15 = lane & 15, lg = lane >> 4;
    const int mt0 = blockIdx.x * 2;

    {
        f32x4 acc[2][3];
        #pragma unroll
        for (int m2 = 0; m2 < 2; ++m2)
            #pragma unroll
            for (int i = 0; i < 3; ++i) acc[m2][i] = (f32x4){0.f, 0.f, 0.f, 0.f};
        for (int kt = 0; kt < 16; ++kt) {
            const unsigned short* ap0 = sf + ((size_t)((mt0 + 0) * 16 + kt) * 64 + lane) * 16;
            const unsigned short* ap1 = sf + ((size_t)((mt0 + 1) * 16 + kt) * 64 + lane) * 16;
            bf16x8 axh0 = *(const bf16x8*)ap0;
            bf16x8 axl0 = *(const bf16x8*)(ap0 + 8);
            bf16x8 axh1 = *(const bf16x8*)ap1;
            bf16x8 axl1 = *(const bf16x8*)(ap1 + 8);
            #pragma unroll
            for (int i = 0; i < 3; ++i) {
                const unsigned short* wp = w1f + ((size_t)((wv * 3 + i) * 16 + kt) * 64 + lane) * 16;
                bf16x8 bh = *(const bf16x8*)wp;
                bf16x8 bl = *(const bf16x8*)(wp + 8);
                acc[0][i] = __builtin_amdgcn_mfma_f32_16x16x32_bf16(bh, axh0, acc[0][i], 0, 0, 0);
                acc[0][i] = __builtin_amdgcn_mfma_f32_16x16x32_bf16(bl, axh0, acc[0][i], 0, 0, 0);
                acc[0][i] = __builtin_amdgcn_mfma_f32_16x16x32_bf16(bh, axl0, acc[0][i], 0, 0, 0);
                acc[1][i] = __builtin_amdgcn_mfma_f32_16x16x32_bf16(bh, axh1, acc[1][i], 0, 0, 0);
                acc[1][i] = __builtin_amdgcn_mfma_f32_16x16x32_bf16(bl, axh1, acc[1][i], 0, 0, 0);
                acc[1][i] = __builtin_amdgcn_mfma_f32_16x16x32_bf16(bh, axl1, acc[1][i], 0, 0, 0);
            }
        }
        #pragma unroll
        for (int m2 = 0; m2 < 2; ++m2) {
            #pragma unroll
            for (int i = 0; i < 3; ++i) {
                const int ntile = wv * 3 + i;
                const int n0 = ntile * 16 + lg * 4;
                f32x4 bv = *(const f32x4*)(b1c + n0);
                f32x4 v = acc[m2][i] + bv;
                ushort4v vh, vl;
                #pragma unroll
                for (int r = 0; r < 4; ++r) {
                    float x = fmaxf(v[r], 0.f);
                    unsigned short hh, ll; split_bf16(x, hh, ll);
                    vh[r] = hh; vl[r] = ll;
                }
                const int ch = ntile * 2 + (lg >> 1);
                const int kt2 = ch >> 2;
                const int lane2 = (ch & 3) * 16 + l15;
                const int e0 = (lg & 1) * 4;
                *(ushort4v*)&h1frag[m2][kt2][lane2][e0] = vh;
                *(ushort4v*)&h1frag[m2][kt2][lane2][e0 + 8] = vl;
            }
        }
    }
    __syncthreads();

    {
        const int c2 = (wv < 4) ? 2 : 1;
        const int ktb = (wv < 2) ? 0 : (wv < 4) ? 4 : 8;
        f32x4 acc[2][2];
        #pragma unroll
        for (int m2 = 0; m2 < 2; ++m2)
            #pragma unroll
            for (int i = 0; i < 2; ++i) acc[m2][i] = (f32x4){0.f, 0.f, 0.f, 0.f};
        for (int kt = ktb; kt < ktb + 4; ++kt) {
            bf16x8 axh0 = *(const bf16x8*)&h1frag[0][kt][lane][0];
            bf16x8 axl0 = *(const bf16x8*)&h1frag[0][kt][lane][8];
            bf16x8 axh1 = *(const bf16x8*)&h1frag[1][kt][lane][0];
            bf16x8 axl1 = *(const bf16x8*)&h1frag[1][kt][lane][8];
            #pragma unroll
            for (int i = 0; i < 2; ++i) {
                if (i < c2) {
                    const int nt = (wv < 4) ? (wv * 2 + i) : (8 + (wv - 4));
                    const unsigned short* wp = w2f + ((size_t)(nt * 12 + kt) * 64 + lane) * 16;
                    bf16x8 bh = *(const bf16x8*)wp;
                    bf16x8 bl = *(const bf16x8*)(wp + 8);
                    acc[0][i] = __builtin_amdgcn_mfma_f32_16x16x32_bf16(bh, axh0, acc[0][i], 0, 0, 0);
                    acc[0][i] = __builtin_amdgcn_mfma_f32_16x16x32_bf16(bl, axh0, acc[0][i], 0, 0, 0);
                    acc[0][i] = __builtin_amdgcn_mfma_f32_16x16x32_bf16(bh, axl0, acc[0][i], 0, 0, 0);
                    acc[1][i] = __builtin_amdgcn_mfma_f32_16x16x32_bf16(bh, axh1, acc[1][i], 0, 0, 0);
                    acc[1][i] = __builtin_amdgcn_mfma_f32_16x16x32_bf16(bl, axh1, acc[1][i], 0, 0, 0);
                    acc[1][i] = __builtin_amdgcn_mfma_f32_16x16x32_bf16(bh, axl1, acc[1][i], 0, 0, 0);
                }
            }
        }
        #pragma unroll
        for (int m2 = 0; m2 < 2; ++m2) {
            #pragma unroll
            for (int i = 0; i < 2; ++i) {
                if (i < c2) {
                    const int ntile = (wv < 4) ? (wv * 2 + i) : (8 + (wv - 4));
                    const int n0 = ntile * 16 + lg * 4;
                    f32x4 bv = *(const f32x4*)(b2c + n0);
                    f32x4 v = acc[m2][i] + bv;
                    ushort4v vh, vl;
                    #pragma unroll
                    for (int r = 0; r < 4; ++r) {
                        float x = fmaxf(v[r], 0.f);
                        unsigned short hh, ll; split_bf16(x, hh, ll);
                        vh[r] = hh; vl[r] = ll;
                    }
                    const int ch = ntile * 2 + (lg >> 1);
                    const int kt2 = ch >> 2;
                    const int lane2 = (ch & 3) * 16 + l15;
                    const int e0 = (lg & 1) * 4;
                    *(ushort4v*)&h2frag[m2][kt2][lane2][e0] = vh;
                    *(ushort4v*)&h2frag[m2][kt2][lane2][e0 + 8] = vl;
                }
            }
        }
    }
    __syncthreads();

    {
        const int c3 = (wv == 0) ? 2 : 1;
        f32x4 acc[2][2];
        #pragma unroll
        for (int m2 = 0; m2 < 2; ++m2)
            #pragma unroll
            for (int i = 0; i < 2; ++i) acc[m2][i] = (f32x4){0.f, 0.f, 0.f, 0.f};
        if (wv == 0) {
            for (int kt = 0; kt < 4; ++kt) {
                const unsigned short* wp = w3f + ((size_t)kt * 64 + lane) * 16;
                bf16x8 bh = *(const bf16x8*)wp;
                bf16x8 bl = *(const bf16x8*)(wp + 8);
                #pragma unroll
                for (int m2 = 0; m2 < 2; ++m2) {
                    bf16x8 axh = *(const bf16x8*)&h2frag[m2][kt][lane][0];
                    bf16x8 axl = *(const bf16x8*)&h2frag[m2][kt][lane][8];
                    acc[m2][0] = __builtin_amdgcn_mfma_f32_16x16x32_bf16(bh, axh, acc[m2][0], 0, 0, 0);
                    acc[m2][0] = __builtin_amdgcn_mfma_f32_16x16x32_bf16(bl, axh, acc[m2][0], 0, 0, 0);
                    acc[m2][0] = __builtin_amdgcn_mfma_f32_16x16x32_bf16(bh, axl, acc[m2][0], 0, 0, 0);
                }
            }
        }
        for (int kt = 4; kt < 6; ++kt) {
            const int nt = (wv == 0) ? 8 : wv;
            const int ai = (wv == 0) ? 1 : 0;
            const unsigned short* wp = w3f + ((size_t)(nt * 6 + kt) * 64 + lane) * 16;
            bf16x8 bh = *(const bf16x8*)wp;
            bf16x8 bl = *(const bf16x8*)(wp + 8);
            #pragma unroll
            for (int m2 = 0; m2 < 2; ++m2) {
                bf16x8 axh = *(const bf16x8*)&h2frag[m2][kt][lane][0];
                bf16x8 axl = *(const bf16x8*)&h2frag[m2][kt][lane][8];
                if (ai == 0) {
                    acc[m2][0] = __builtin_amdgcn_mfma_f32_16x16x32_bf16(bh, axh, acc[m2][0], 0, 0, 0);
                    acc[m2][0] = __builtin_amdgcn_mfma_f32_16x16x32_bf16(bl, axh, acc[m2][0], 0, 0, 0);
                    acc[m2][0] = __builtin_amdgcn_mfma_f32_16x16x32_bf16(bh, axl, acc[m2][0], 0, 0, 0);
                } else {
                    acc[m2][1] = __builtin_amdgcn_mfma_f32_16x16x32_bf16(bh, axh, acc[m2][1], 0, 0, 0);
                    acc[m2][1] = __builtin_amdgcn_mfma_f32_16x16x32_bf16(bl, axh, acc[m2][1], 0, 0, 0);
                    acc[m2][1] = __builtin_amdgcn_mfma_f32_16x16x32_bf16(bh, axl, acc[m2][1], 0, 0, 0);
                }
            }
        }
        float ssq[2] = {0.f, 0.f};
        float pred[2] = {0.f, 0.f}, tgt[2] = {0.f, 0.f};
        #pragma unroll
        for (int m2 = 0; m2 < 2; ++m2) {
            #pragma unroll
            for (int i = 0; i < 2; ++i) {
                if (i < c3) {
                    const int ntg = (i == 0) ? wv : 8;
                    const int n0 = ntg * 16 + lg * 4;
                    f32x4 bv = *(const f32x4*)(b3c + n0);
                    f32x4 v = acc[m2][i] + bv;
                    if (ntg == 0) {
                        if (lg == 0) { pred[m2] = v.x; tgt[m2] = v.y; }
                    } else {
                        ushort4v zu;
                        #pragma unroll
                        for (int r = 0; r < 4; ++r) {
                            unsigned short us = f32_to_bf16_rne(v[r]);
                            float zf32 = __uint_as_float(((unsigned int)us) << 16);
                            ssq[m2] += zf32 * zf32;
                            zu[r] = us;
                        }
                        // 32-row fragment layout: ctile=blockIdx, kc=ntg-1,
                        // lane2=row32 + 32*k_hi, j0=(d&7) base
                        const int kc = ntg - 1;
                        const int lane2 = m2 * 16 + l15 + 32 * ((lg >> 1) & 1);
                        const int j0 = (lg & 1) * 4;
                        *(ushort4v*)(zf + ((size_t)(blockIdx.x * 8 + kc) * 64 + lane2) * 8 + j0) = zu;
                    }
                }
            }
        }
        #pragma unroll
        for (int m2 = 0; m2 < 2; ++m2) {
            float sv = ssq[m2];
            sv += __shfl_xor(sv, 16);
            sv += __shfl_xor(sv, 32);
            if (lg == 0) sred[m2][wv][l15] = sv;
        }
        __syncthreads();
        if (t < 32) {
            const int m2 = t >> 4, idx = t & 15;
            float sm = 0.f;
            #pragma unroll
            for (int w8 = 0; w8 < 8; ++w8) sm += sred[m2][w8][idx];
            sq[(mt0 + m2) * 16 + idx] = sm;
        }
        if (wv == 0 && lg == 0) {
            #pragma unroll
            for (int m2 = 0; m2 < 2; ++m2) {
                float d = pred[m2] - tgt[m2];
                alpha[(mt0 + m2) * 16 + l15] = d * d;
            }
        }
    }
}

// ---------------- K1b: threshold pre-pass, 32x32x16 MFMA (split 0; writes part[0]) ----------------
// 64 blocks x 256 thr; wave = 32 queries x 512 samples (16 ctiles).
__global__ __launch_bounds__(256, 2) void k_thr(
    const unsigned short* __restrict__ zf, const float* __restrict__ sq,
    float* __restrict__ thrA, float* __restrict__ part)
{
    __shared__ float buf[4][64][BCAP];
    __shared__ float sqs[512];
    const int t = threadIdx.x;
    const int lane = t & 63, wv = t >> 6;
    const int l31 = lane & 31, hi = lane >> 5;
    const int qt = blockIdx.x * 4 + wv;   // 256 q-tiles

    sqs[t] = sq[t];
    sqs[t + 256] = sq[t + 256];
    __syncthreads();

    float* bp = &buf[wv][lane][0];
    const int qid = qt * 32 + l31;
    bf16x8 bq[8];
    #pragma unroll
    for (int kc = 0; kc < 8; ++kc)
        bq[kc] = *(const bf16x8*)(zf + ((size_t)(qt * 8 + kc) * 64 + lane) * 8);

    float vals[K2];
    #pragma unroll
    for (int i = 0; i < K2; ++i) vals[i] = BIGF;
    float thr = BIGF;
    int cnt = 0;

    bf16x8 av[8];
    #pragma unroll
    for (int kc = 0; kc < 8; ++kc)
        av[kc] = *(const bf16x8*)(zf + ((size_t)kc * 64 + lane) * 8);

    for (int i = 0; i < 16; ++i) {
        f32x16 acc = {};
        #pragma unroll
        for (int kc = 0; kc < 8; ++kc)
            acc = __builtin_amdgcn_mfma_f32_32x32x16_bf16(av[kc], bq[kc], acc, 0, 0, 0);
        if (i < 15) {
            #pragma unroll
            for (int kc = 0; kc < 8; ++kc)
                av[kc] = *(const bf16x8*)(zf + ((size_t)((i + 1) * 8 + kc) * 64 + lane) * 8);
        }
        #pragma unroll
        for (int g = 0; g < 2; ++g) {
            f32x4 sqv = *(const f32x4*)(&sqs[i * 32 + 8 * g + 4 * hi]);
            #pragma unroll
            for (int rr = 0; rr < 4; ++rr) {
                float v = fmaf(-2.0f, acc[g * 4 + rr], sqv[rr]);
                bp[cnt] = v;
                cnt += (int)(v <= thr);
            }
        }
        if (__any(cnt >= TRIG)) { compactB(vals, bp, cnt); thr = vals[K2 - 1]; cnt = 0; }
        #pragma unroll
        for (int g = 2; g < 4; ++g) {
            f32x4 sqv = *(const f32x4*)(&sqs[i * 32 + 8 * g + 4 * hi]);
            #pragma unroll
            for (int rr = 0; rr < 4; ++rr) {
                float v = fmaf(-2.0f, acc[g * 4 + rr], sqv[rr]);
                bp[cnt] = v;
                cnt += (int)(v <= thr);
            }
        }
        if (__any(cnt >= TRIG)) { compactB(vals, bp, cnt); thr = vals[K2 - 1]; cnt = 0; }
    }
    compactB(vals, bp, cnt);

    // merge lane l <-> l+32 (same query): min-trick then sort
    float wk[K2];
    #pragma unroll
    for (int i = 0; i < K2; ++i) {
        float o = __shfl_xor(vals[K2 - 1 - i], 32);
        wk[i] = fminf(vals[i], o);
    }
    sortBitonic11(wk);
    if (lane < 32) {
        thrA[qid] = wk[K2 - 1];
        float* dst = part + (size_t)qid * K2;
        #pragma unroll
        for (int i = 0; i < K2; ++i) dst[i] = wk[i];
    }
}

// ---------------- K2: pairwise 32x32x16 + sample-thresholded top-11 (splits 1..15) ----------------
// 960 blocks x 256 thr; split = 1 + b%15, qt = (b/15)*4 + wave; 32 q x 512 cands (16 ctiles).
__global__ __launch_bounds__(256, 2) void k_pairs(
    const unsigned short* __restrict__ zf, const float* __restrict__ sq,
    const float* __restrict__ thrA, float* __restrict__ part)
{
    __shared__ float buf[4][64][BCAP];
    __shared__ float sqs[512];
    const int t = threadIdx.x;
    const int lane = t & 63, wv = t >> 6;
    const int l31 = lane & 31, hi = lane >> 5;
    const int split = 1 + (blockIdx.x % 15);
    const int qt = (blockIdx.x / 15) * 4 + wv;
    const int c0 = split * 512;
    const int ct0 = split * 16;

    sqs[t] = sq[c0 + t];
    sqs[t + 256] = sq[c0 + t + 256];
    __syncthreads();

    float* bp = &buf[wv][lane][0];
    const int qid = qt * 32 + l31;
    bf16x8 bq[8];
    #pragma unroll
    for (int kc = 0; kc < 8; ++kc)
        bq[kc] = *(const bf16x8*)(zf + ((size_t)(qt * 8 + kc) * 64 + lane) * 8);
    float thr = thrA[qid];

    float vals[K2];
    #pragma unroll
    for (int i = 0; i < K2; ++i) vals[i] = BIGF;
    int cnt = 0;

    bf16x8 avA[8], avB[8];
    #pragma unroll
    for (int kc = 0; kc < 8; ++kc)
        avA[kc] = *(const bf16x8*)(zf + ((size_t)(ct0 * 8 + kc) * 64 + lane) * 8);
    #pragma unroll
    for (int kc = 0; kc < 8; ++kc)
        avB[kc] = *(const bf16x8*)(zf + ((size_t)((ct0 + 1) * 8 + kc) * 64 + lane) * 8);

    for (int i = 0; i < 16; i += 2) {
        {   // even ctile (avA)
            f32x16 acc = {};
            #pragma unroll
            for (int kc = 0; kc < 8; ++kc)
                acc = __builtin_amdgcn_mfma_f32_32x32x16_bf16(avA[kc], bq[kc], acc, 0, 0, 0);
            if (i + 2 < 16) {
                #pragma unroll
                for (int kc = 0; kc < 8; ++kc)
                    avA[kc] = *(const bf16x8*)(zf + ((size_t)((ct0 + i + 2) * 8 + kc) * 64 + lane) * 8);
            }
            #pragma unroll
            for (int g = 0; g < 2; ++g) {
                f32x4 sqv = *(const f32x4*)(&sqs[i * 32 + 8 * g + 4 * hi]);
                #pragma unroll
                for (int rr = 0; rr < 4; ++rr) {
                    float v = fmaf(-2.0f, acc[g * 4 + rr], sqv[rr]);
                    bp[cnt] = v;
                    cnt += (int)(v <= thr);
                }
            }
            if (__any(cnt >= TRIG)) { compactB(vals, bp, cnt); thr = fminf(thr, vals[K2 - 1]); cnt = 0; }
            #pragma unroll
            for (int g = 2; g < 4; ++g) {
                f32x4 sqv = *(const f32x4*)(&sqs[i * 32 + 8 * g + 4 * hi]);
                #pragma unroll
                for (int rr = 0; rr < 4; ++rr) {
                    float v = fmaf(-2.0f, acc[g * 4 + rr], sqv[rr]);
                    bp[cnt] = v;
                    cnt += (int)(v <= thr);
                }
            }
            if (__any(cnt >= TRIG)) { compactB(vals, bp, cnt); thr = fminf(thr, vals[K2 - 1]); cnt = 0; }
        }
        {   // odd ctile (avB)
            f32x16 acc = {};
            #pragma unroll
            for (int kc = 0; kc < 8; ++kc)
                acc = __builtin_amdgcn_mfma_f32_32x32x16_bf16(avB[kc], bq[kc], acc, 0, 0, 0);
            if (i + 3 < 16) {
                #pragma unroll
                for (int kc = 0; kc < 8; ++kc)
                    avB[kc] = *(const bf16x8*)(zf + ((size_t)((ct0 + i + 3) * 8 + kc) * 64 + lane) * 8);
            }
            const int ib = i + 1;
            #pragma unroll
            for (int g = 0; g < 2; ++g) {
                f32x4 sqv = *(const f32x4*)(&sqs[ib * 32 + 8 * g + 4 * hi]);
                #pragma unroll
                for (int rr = 0; rr < 4; ++rr) {
                    float v = fmaf(-2.0f, acc[g * 4 + rr], sqv[rr]);
                    bp[cnt] = v;
                    cnt += (int)(v <= thr);
                }
            }
            if (__any(cnt >= TRIG)) { compactB(vals, bp, cnt); thr = fminf(thr, vals[K2 - 1]); cnt = 0; }
            #pragma unroll
            for (int g = 2; g < 4; ++g) {
                f32x4 sqv = *(const f32x4*)(&sqs[ib * 32 + 8 * g + 4 * hi]);
                #pragma unroll
                for (int rr = 0; rr < 4; ++rr) {
                    float v = fmaf(-2.0f, acc[g * 4 + rr], sqv[rr]);
                    bp[cnt] = v;
                    cnt += (int)(v <= thr);
                }
            }
            if (__any(cnt >= TRIG)) { compactB(vals, bp, cnt); thr = fminf(thr, vals[K2 - 1]); cnt = 0; }
        }
    }
    compactB(vals, bp, cnt);

    float wk[K2];
    #pragma unroll
    for (int i = 0; i < K2; ++i) {
        float o = __shfl_xor(vals[K2 - 1 - i], 32);
        wk[i] = fminf(vals[i], o);
    }
    sortBitonic11(wk);
    if (lane < 32) {
        float* dst = part + ((size_t)split * NROWS + qid) * K2;
        #pragma unroll
        for (int i = 0; i < K2; ++i) dst[i] = wk[i];
    }
}

// ---------------- K3: merge 16 partial 11-lists (2 threads/q x 8 segs); drop min (self) ----------------
__global__ __launch_bounds__(256) void k_merge(
    const float* __restrict__ part, const float* __restrict__ sq,
    float* __restrict__ sumk, float* __restrict__ total)
{
    __shared__ float xb[128][K2 + 1];
    __shared__ float red[4];
    const int t = threadIdx.x;
    const int qi = t & 127, hf = t >> 7;
    const int q = blockIdx.x * 128 + qi;

    float vals[K2];
    #pragma unroll
    for (int i = 0; i < K2; ++i) vals[i] = BIGF;
    for (int seg = hf * 8; seg < hf * 8 + 8; ++seg) {
        const float* p = part + ((size_t)seg * NROWS + q) * K2;
        #pragma unroll
        for (int i = 0; i < K2; ++i) {
            float tv = p[i];
            if (tv < vals[K2 - 1]) insert11(vals, tv);
        }
    }
    if (hf) {
        #pragma unroll
        for (int i = 0; i < K2; ++i) xb[qi][i] = vals[i];
    }
    __syncthreads();
    float sum = 0.f;
    if (!hf) {
        #pragma unroll
        for (int i = 0; i < K2; ++i) {
            float tv = xb[qi][i];
            if (tv < vals[K2 - 1]) insert11(vals, tv);
        }
        float sqq = sq[q];
        #pragma unroll
        for (int i = 1; i < K2; ++i) {
            float raw = sqq + vals[i];
            sum += (raw > 0.f) ? sqrtf(raw) : 0.f;
        }
        sumk[q] = sum;
    }
    #pragma unroll
    for (int off = 32; off > 0; off >>= 1) sum += __shfl_down(sum, off);
    if ((t & 63) == 0) red[t >> 6] = sum;
    __syncthreads();
    if (t == 0) atomicAdd(total, red[0] + red[1] + red[2] + red[3]);
}

// ---------------- K4: finalize ----------------
__global__ __launch_bounds__(256) void k_final(
    const float* __restrict__ sumk, const float* __restrict__ alpha,
    const float* __restrict__ total, float* __restrict__ out)
{
    const int q = blockIdx.x * 256 + threadIdx.x;
    float mean = (*total) * (1.0f / NROWS);
    float m2 = mean * mean;
    float sk = sumk[q];
    float x = (sk * sk) / m2;
    float knn = EPS_CONST / (x + EPS_CONST);
    float rep = 1.0f / (sqrtf(knn) + C_CONST);
    float a = alpha[q];
    a = fminf(fmaxf(a, 1.0f), L_CONST);
    out[q] = rep * a;
}

extern "C" void kernel_launch(void* const* d_in, const int* in_sizes, int n_in,
                              void* d_out, int out_size, void* d_ws, size_t ws_size,
                              hipStream_t stream) {
    const float* s   = (const float*)d_in[0];
    const float* w1  = (const float*)d_in[1];
    const float* b1  = (const float*)d_in[2];
    const float* w2  = (const float*)d_in[3];
    const float* b2  = (const float*)d_in[4];
    const float* w3  = (const float*)d_in[5];
    const float* b3  = (const float*)d_in[6];
    const float* wt1 = (const float*)d_in[7];
    const float* bt1 = (const float*)d_in[8];
    const float* wt2 = (const float*)d_in[9];
    const float* bt2 = (const float*)d_in[10];
    const float* wt3 = (const float*)d_in[11];
    const float* bt3 = (const float*)d_in[12];
    const float* wz1 = (const float*)d_in[13];
    const float* bz1 = (const float*)d_in[14];
    const float* wz2 = (const float*)d_in[15];
    const float* bz2 = (const float*)d_in[16];
    const float* wz3 = (const float*)d_in[17];
    const float* bz3 = (const float*)d_in[18];

    char* ws = (char*)d_ws;
    unsigned short* zf  = (unsigned short*)(ws);                // 2097152
    float* sq    = (float*)(ws + 2097152);                      // 32768
    float* alpha = (float*)(ws + 2129920);                      // 32768
    float* part  = (float*)(ws + 2162688);                      // 16*8192*11*4 = 5767168
    float* sumk  = (float*)(ws + 13697024);                     // 32768
    float* total = (float*)(ws + 13729792);                     // 256
    float* thrA  = (float*)(ws + 13730048);                     // 32768
    unsigned short* w1f = (unsigned short*)(ws + 13762816);     // 786432
    unsigned short* w2f = (unsigned short*)(ws + 14549248);     // 294912
    unsigned short* w3f = (unsigned short*)(ws + 14844160);     // 110592
    float* b1c = (float*)(ws + 14954752);
    float* b2c = (float*)(ws + 14956288);
    float* b3c = (float*)(ws + 14957056);
    unsigned short* sf  = (unsigned short*)(ws + 14958592);     // 16777216

    k_prepw<<<2195, 256, 0, stream>>>(s,
                                      w1, wt1, wz1, w2, wt2, wz2, w3, wt3, wz3,
                                      b1, bt1, bz1, b2, bt2, bz2, b3, bt3, bz3,
                                      sf, w1f, w2f, w3f, b1c, b2c, b3c, total);
    k_mlp<<<256, 512, 0, stream>>>(sf, w1f, w2f, w3f, b1c, b2c, b3c, zf, sq, alpha);
    k_thr<<<64, 256, 0, stream>>>(zf, sq, thrA, part);
    k_pairs<<<960, 256, 0, stream>>>(zf, sq, thrA, part);
    k_merge<<<64, 256, 0, stream>>>(part, sq, sumk, total);
    k_final<<<32, 256, 0, stream>>>(sumk, alpha, total, (float*)d_out);
}

// Round 19
// 100.723 us; speedup vs baseline: 1.0886x; 1.0886x over previous
//
#include <hip/hip_runtime.h>
#include <hip/hip_bf16.h>

#define NROWS 8192
#define FDIM 128
#define KNN 10
#define K2 11
#define C_CONST 1.0e-3f
#define L_CONST 5.0f
#define EPS_CONST 1.0e-3f
#define BIGF 3.0e38f
#define BCAP 9
#define TRIG 6

typedef float f32x4 __attribute__((ext_vector_type(4)));
typedef __bf16 bf16x8 __attribute__((ext_vector_type(8)));
typedef unsigned short ushort4v __attribute__((ext_vector_type(4)));
typedef unsigned short ushort8v __attribute__((ext_vector_type(8)));

__device__ __forceinline__ unsigned short f32_to_bf16_rne(float f) {
    unsigned int x = __float_as_uint(f);
    unsigned int lsb = (x >> 16) & 1u;
    x += 0x7fffu + lsb;
    return (unsigned short)(x >> 16);
}

__device__ __forceinline__ void split_bf16(float v, unsigned short& h, unsigned short& l) {
    unsigned short hh = f32_to_bf16_rne(v);
    float hf = __uint_as_float(((unsigned int)hh) << 16);
    h = hh;
    l = f32_to_bf16_rne(v - hf);
}

__device__ __forceinline__ void insert11(float* v, float tv) {
    #pragma unroll
    for (int u = 0; u < K2; ++u) {
        float lo = fminf(v[u], tv);
        tv = fmaxf(v[u], tv);
        v[u] = lo;
    }
}

__device__ __forceinline__ void compactB(float* v, const float* bp, int cnt) {
    #pragma unroll
    for (int i = 0; i < BCAP; ++i) {
        float tv = (i < cnt) ? bp[i] : BIGF;
        insert11(v, tv);
    }
}

__device__ __forceinline__ void ce(float& a, float& b) {
    float lo = fminf(a, b), hi = fmaxf(a, b); a = lo; b = hi;
}
__device__ __forceinline__ void sortBitonic11(float* w) {
    ce(w[0],w[8]); ce(w[1],w[9]); ce(w[2],w[10]);
    ce(w[0],w[4]); ce(w[1],w[5]); ce(w[2],w[6]); ce(w[3],w[7]);
    ce(w[0],w[2]); ce(w[1],w[3]); ce(w[4],w[6]); ce(w[5],w[7]); ce(w[8],w[10]);
    ce(w[0],w[1]); ce(w[2],w[3]); ce(w[4],w[5]); ce(w[6],w[7]); ce(w[8],w[9]);
}

// ---------------- K0: prep (s fragment split + weight frag + biases + zero total) ----------------
__global__ __launch_bounds__(256) void k_prepw(
    const float* __restrict__ s,
    const float* __restrict__ w1, const float* __restrict__ wt1, const float* __restrict__ wz1,
    const float* __restrict__ w2, const float* __restrict__ wt2, const float* __restrict__ wz2,
    const float* __restrict__ w3, const float* __restrict__ wt3, const float* __restrict__ wz3,
    const float* __restrict__ b1, const float* __restrict__ bt1, const float* __restrict__ bz1,
    const float* __restrict__ b2, const float* __restrict__ bt2, const float* __restrict__ bz2,
    const float* __restrict__ b3, const float* __restrict__ bt3, const float* __restrict__ bz3,
    unsigned short* __restrict__ sf,
    unsigned short* __restrict__ w1f, unsigned short* __restrict__ w2f,
    unsigned short* __restrict__ w3f,
    float* __restrict__ b1c, float* __restrict__ b2c, float* __restrict__ b3c,
    float* __restrict__ total)
{
    const int b = blockIdx.x;
    const int t = threadIdx.x;
    const int wv = t >> 6, lane = t & 63;
    const int l15 = lane & 15, lg = lane >> 4;

    if (b < 2048) {
        const int w = b * 4 + wv;
        const int mt = w >> 4, kt = w & 15;
        const float* src = s + (size_t)(mt * 16 + l15) * 512 + kt * 32 + lg * 8;
        f32x4 a = *(const f32x4*)src;
        f32x4 c = *(const f32x4*)(src + 4);
        ushort8v h, l;
        #pragma unroll
        for (int j = 0; j < 4; ++j) {
            unsigned short hh, ll;
            split_bf16(a[j], hh, ll); h[j] = hh; l[j] = ll;
            split_bf16(c[j], hh, ll); h[4 + j] = hh; l[4 + j] = ll;
        }
        unsigned short* dst = sf + ((size_t)(mt * 16 + kt) * 64 + lane) * 16;
        *(ushort8v*)dst = h;
        *(ushort8v*)(dst + 8) = l;
    } else if (b < 2144) {
        const int w = (b - 2048) * 4 + wv;
        const int nt = w >> 4, kt = w & 15;
        const int n = nt * 16 + l15, k = kt * 32 + lg * 8;
        const float* src = (n < 128) ? (w1 + (size_t)n * 512 + k)
                         : (n < 256) ? (wt1 + (size_t)(n - 128) * 512 + k)
                                     : (wz1 + (size_t)(n - 256) * 512 + k);
        f32x4 a = *(const f32x4*)src;
        f32x4 c = *(const f32x4*)(src + 4);
        ushort8v h, l;
        #pragma unroll
        for (int j = 0; j < 4; ++j) {
            unsigned short hh, ll;
            split_bf16(a[j], hh, ll); h[j] = hh; l[j] = ll;
            split_bf16(c[j], hh, ll); h[4 + j] = hh; l[4 + j] = ll;
        }
        unsigned short* dst = w1f + ((size_t)(nt * 16 + kt) * 64 + lane) * 16;
        *(ushort8v*)dst = h;
        *(ushort8v*)(dst + 8) = l;
    } else if (b < 2180) {
        const int w = (b - 2144) * 4 + wv;
        const int nt = w / 12, kt = w % 12;
        const int n = nt * 16 + l15, k = kt * 32 + lg * 8;
        f32x4 a = {0.f,0.f,0.f,0.f}, c = {0.f,0.f,0.f,0.f};
        if (n < 64)       { if (k < 128)             { const float* p = w2  + (size_t)n * 128 + k;                 a = *(const f32x4*)p; c = *(const f32x4*)(p + 4); } }
        else if (n < 128) { if (k >= 128 && k < 256) { const float* p = wt2 + (size_t)(n - 64) * 128 + (k - 128);  a = *(const f32x4*)p; c = *(const f32x4*)(p + 4); } }
        else              { if (k >= 256)            { const float* p = wz2 + (size_t)(n - 128) * 128 + (k - 256); a = *(const f32x4*)p; c = *(const f32x4*)(p + 4); } }
        ushort8v h, l;
        #pragma unroll
        for (int j = 0; j < 4; ++j) {
            unsigned short hh, ll;
            split_bf16(a[j], hh, ll); h[j] = hh; l[j] = ll;
            split_bf16(c[j], hh, ll); h[4 + j] = hh; l[4 + j] = ll;
        }
        unsigned short* dst = w2f + ((size_t)(nt * 12 + kt) * 64 + lane) * 16;
        *(ushort8v*)dst = h;
        *(ushort8v*)(dst + 8) = l;
    } else if (b < 2194) {
        const int w = (b - 2180) * 4 + wv;
        if (w < 54) {
            const int nt = w / 6, kt = w % 6;
            const int n = nt * 16 + l15, k = kt * 32 + lg * 8;
            f32x4 a = {0.f,0.f,0.f,0.f}, c = {0.f,0.f,0.f,0.f};
            if (n == 0)                  { if (k < 64)             { const float* p = w3 + k;                                   a = *(const f32x4*)p; c = *(const f32x4*)(p + 4); } }
            else if (n == 1)             { if (k >= 64 && k < 128) { const float* p = wt3 + (k - 64);                           a = *(const f32x4*)p; c = *(const f32x4*)(p + 4); } }
            else if (n >= 16 && n < 144) { if (k >= 128)           { const float* p = wz3 + (size_t)(n - 16) * 64 + (k - 128);  a = *(const f32x4*)p; c = *(const f32x4*)(p + 4); } }
            ushort8v h, l;
            #pragma unroll
            for (int j = 0; j < 4; ++j) {
                unsigned short hh, ll;
                split_bf16(a[j], hh, ll); h[j] = hh; l[j] = ll;
                split_bf16(c[j], hh, ll); h[4 + j] = hh; l[4 + j] = ll;
            }
            unsigned short* dst = w3f + ((size_t)(nt * 6 + kt) * 64 + lane) * 16;
            *(ushort8v*)dst = h;
            *(ushort8v*)(dst + 8) = l;
        }
    } else {
        if (t == 0) *total = 0.f;
        for (int i = t; i < 720; i += 256) {
            if (i < 384)      b1c[i] = (i < 128) ? b1[i] : (i < 256) ? bt1[i - 128] : bz1[i - 256];
            else if (i < 576) { int j = i - 384; b2c[j] = (j < 64) ? b2[j] : (j < 128) ? bt2[j - 64] : bz2[j - 128]; }
            else              { int j = i - 576; b3c[j] = (j == 0) ? b3[0] : (j == 1) ? bt3[0] : (j < 16) ? 0.f : bz3[j - 16]; }
        }
    }
}

// ---------------- K1: fused 3-layer MLP, 2 m-tiles/block; sf read from global ----------------
__global__ __launch_bounds__(512, 4) void k_mlp(
    const unsigned short* __restrict__ sf,
    const unsigned short* __restrict__ w1f, const unsigned short* __restrict__ w2f,
    const unsigned short* __restrict__ w3f,
    const float* __restrict__ b1c, const float* __restrict__ b2c, const float* __restrict__ b3c,
    unsigned short* __restrict__ zf, float* __restrict__ sq, float* __restrict__ alpha)
{
    __shared__ unsigned short h1frag[2][12][64][16];
    __shared__ unsigned short h2frag[2][6][64][16];
    __shared__ float sred[2][8][16];

    const int t = threadIdx.x;
    const int lane = t & 63, wv = t >> 6;
    const int l15 = lane & 15, lg = lane >> 4;
    const int mt0 = blockIdx.x * 2;

    {
        f32x4 acc[2][3];
        #pragma unroll
        for (int m2 = 0; m2 < 2; ++m2)
            #pragma unroll
            for (int i = 0; i < 3; ++i) acc[m2][i] = (f32x4){0.f, 0.f, 0.f, 0.f};
        for (int kt = 0; kt < 16; ++kt) {
            const unsigned short* ap0 = sf + ((size_t)((mt0 + 0) * 16 + kt) * 64 + lane) * 16;
            const unsigned short* ap1 = sf + ((size_t)((mt0 + 1) * 16 + kt) * 64 + lane) * 16;
            bf16x8 axh0 = *(const bf16x8*)ap0;
            bf16x8 axl0 = *(const bf16x8*)(ap0 + 8);
            bf16x8 axh1 = *(const bf16x8*)ap1;
            bf16x8 axl1 = *(const bf16x8*)(ap1 + 8);
            #pragma unroll
            for (int i = 0; i < 3; ++i) {
                const unsigned short* wp = w1f + ((size_t)((wv * 3 + i) * 16 + kt) * 64 + lane) * 16;
                bf16x8 bh = *(const bf16x8*)wp;
                bf16x8 bl = *(const bf16x8*)(wp + 8);
                acc[0][i] = __builtin_amdgcn_mfma_f32_16x16x32_bf16(bh, axh0, acc[0][i], 0, 0, 0);
                acc[0][i] = __builtin_amdgcn_mfma_f32_16x16x32_bf16(bl, axh0, acc[0][i], 0, 0, 0);
                acc[0][i] = __builtin_amdgcn_mfma_f32_16x16x32_bf16(bh, axl0, acc[0][i], 0, 0, 0);
                acc[1][i] = __builtin_amdgcn_mfma_f32_16x16x32_bf16(bh, axh1, acc[1][i], 0, 0, 0);
                acc[1][i] = __builtin_amdgcn_mfma_f32_16x16x32_bf16(bl, axh1, acc[1][i], 0, 0, 0);
                acc[1][i] = __builtin_amdgcn_mfma_f32_16x16x32_bf16(bh, axl1, acc[1][i], 0, 0, 0);
            }
        }
        #pragma unroll
        for (int m2 = 0; m2 < 2; ++m2) {
            #pragma unroll
            for (int i = 0; i < 3; ++i) {
                const int ntile = wv * 3 + i;
                const int n0 = ntile * 16 + lg * 4;
                f32x4 bv = *(const f32x4*)(b1c + n0);
                f32x4 v = acc[m2][i] + bv;
                ushort4v vh, vl;
                #pragma unroll
                for (int r = 0; r < 4; ++r) {
                    float x = fmaxf(v[r], 0.f);
                    unsigned short hh, ll; split_bf16(x, hh, ll);
                    vh[r] = hh; vl[r] = ll;
                }
                const int ch = ntile * 2 + (lg >> 1);
                const int kt2 = ch >> 2;
                const int lane2 = (ch & 3) * 16 + l15;
                const int e0 = (lg & 1) * 4;
                *(ushort4v*)&h1frag[m2][kt2][lane2][e0] = vh;
                *(ushort4v*)&h1frag[m2][kt2][lane2][e0 + 8] = vl;
            }
        }
    }
    __syncthreads();

    {
        const int c2 = (wv < 4) ? 2 : 1;
        const int ktb = (wv < 2) ? 0 : (wv < 4) ? 4 : 8;
        f32x4 acc[2][2];
        #pragma unroll
        for (int m2 = 0; m2 < 2; ++m2)
            #pragma unroll
            for (int i = 0; i < 2; ++i) acc[m2][i] = (f32x4){0.f, 0.f, 0.f, 0.f};
        for (int kt = ktb; kt < ktb + 4; ++kt) {
            bf16x8 axh0 = *(const bf16x8*)&h1frag[0][kt][lane][0];
            bf16x8 axl0 = *(const bf16x8*)&h1frag[0][kt][lane][8];
            bf16x8 axh1 = *(const bf16x8*)&h1frag[1][kt][lane][0];
            bf16x8 axl1 = *(const bf16x8*)&h1frag[1][kt][lane][8];
            #pragma unroll
            for (int i = 0; i < 2; ++i) {
                if (i < c2) {
                    const int nt = (wv < 4) ? (wv * 2 + i) : (8 + (wv - 4));
                    const unsigned short* wp = w2f + ((size_t)(nt * 12 + kt) * 64 + lane) * 16;
                    bf16x8 bh = *(const bf16x8*)wp;
                    bf16x8 bl = *(const bf16x8*)(wp + 8);
                    acc[0][i] = __builtin_amdgcn_mfma_f32_16x16x32_bf16(bh, axh0, acc[0][i], 0, 0, 0);
                    acc[0][i] = __builtin_amdgcn_mfma_f32_16x16x32_bf16(bl, axh0, acc[0][i], 0, 0, 0);
                    acc[0][i] = __builtin_amdgcn_mfma_f32_16x16x32_bf16(bh, axl0, acc[0][i], 0, 0, 0);
                    acc[1][i] = __builtin_amdgcn_mfma_f32_16x16x32_bf16(bh, axh1, acc[1][i], 0, 0, 0);
                    acc[1][i] = __builtin_amdgcn_mfma_f32_16x16x32_bf16(bl, axh1, acc[1][i], 0, 0, 0);
                    acc[1][i] = __builtin_amdgcn_mfma_f32_16x16x32_bf16(bh, axl1, acc[1][i], 0, 0, 0);
                }
            }
        }
        #pragma unroll
        for (int m2 = 0; m2 < 2; ++m2) {
            #pragma unroll
            for (int i = 0; i < 2; ++i) {
                if (i < c2) {
                    const int ntile = (wv < 4) ? (wv * 2 + i) : (8 + (wv - 4));
                    const int n0 = ntile * 16 + lg * 4;
                    f32x4 bv = *(const f32x4*)(b2c + n0);
                    f32x4 v = acc[m2][i] + bv;
                    ushort4v vh, vl;
                    #pragma unroll
                    for (int r = 0; r < 4; ++r) {
                        float x = fmaxf(v[r], 0.f);
                        unsigned short hh, ll; split_bf16(x, hh, ll);
                        vh[r] = hh; vl[r] = ll;
                    }
                    const int ch = ntile * 2 + (lg >> 1);
                    const int kt2 = ch >> 2;
                    const int lane2 = (ch & 3) * 16 + l15;
                    const int e0 = (lg & 1) * 4;
                    *(ushort4v*)&h2frag[m2][kt2][lane2][e0] = vh;
                    *(ushort4v*)&h2frag[m2][kt2][lane2][e0 + 8] = vl;
                }
            }
        }
    }
    __syncthreads();

    {
        const int c3 = (wv == 0) ? 2 : 1;
        f32x4 acc[2][2];
        #pragma unroll
        for (int m2 = 0; m2 < 2; ++m2)
            #pragma unroll
            for (int i = 0; i < 2; ++i) acc[m2][i] = (f32x4){0.f, 0.f, 0.f, 0.f};
        if (wv == 0) {
            for (int kt = 0; kt < 4; ++kt) {
                const unsigned short* wp = w3f + ((size_t)kt * 64 + lane) * 16;
                bf16x8 bh = *(const bf16x8*)wp;
                bf16x8 bl = *(const bf16x8*)(wp + 8);
                #pragma unroll
                for (int m2 = 0; m2 < 2; ++m2) {
                    bf16x8 axh = *(const bf16x8*)&h2frag[m2][kt][lane][0];
                    bf16x8 axl = *(const bf16x8*)&h2frag[m2][kt][lane][8];
                    acc[m2][0] = __builtin_amdgcn_mfma_f32_16x16x32_bf16(bh, axh, acc[m2][0], 0, 0, 0);
                    acc[m2][0] = __builtin_amdgcn_mfma_f32_16x16x32_bf16(bl, axh, acc[m2][0], 0, 0, 0);
                    acc[m2][0] = __builtin_amdgcn_mfma_f32_16x16x32_bf16(bh, axl, acc[m2][0], 0, 0, 0);
                }
            }
        }
        for (int kt = 4; kt < 6; ++kt) {
            const int nt = (wv == 0) ? 8 : wv;
            const int ai = (wv == 0) ? 1 : 0;
            const unsigned short* wp = w3f + ((size_t)(nt * 6 + kt) * 64 + lane) * 16;
            bf16x8 bh = *(const bf16x8*)wp;
            bf16x8 bl = *(const bf16x8*)(wp + 8);
            #pragma unroll
            for (int m2 = 0; m2 < 2; ++m2) {
                bf16x8 axh = *(const bf16x8*)&h2frag[m2][kt][lane][0];
                bf16x8 axl = *(const bf16x8*)&h2frag[m2][kt][lane][8];
                if (ai == 0) {
                    acc[m2][0] = __builtin_amdgcn_mfma_f32_16x16x32_bf16(bh, axh, acc[m2][0], 0, 0, 0);
                    acc[m2][0] = __builtin_amdgcn_mfma_f32_16x16x32_bf16(bl, axh, acc[m2][0], 0, 0, 0);
                    acc[m2][0] = __builtin_amdgcn_mfma_f32_16x16x32_bf16(bh, axl, acc[m2][0], 0, 0, 0);
                } else {
                    acc[m2][1] = __builtin_amdgcn_mfma_f32_16x16x32_bf16(bh, axh, acc[m2][1], 0, 0, 0);
                    acc[m2][1] = __builtin_amdgcn_mfma_f32_16x16x32_bf16(bl, axh, acc[m2][1], 0, 0, 0);
                    acc[m2][1] = __builtin_amdgcn_mfma_f32_16x16x32_bf16(bh, axl, acc[m2][1], 0, 0, 0);
                }
            }
        }
        float ssq[2] = {0.f, 0.f};
        float pred[2] = {0.f, 0.f}, tgt[2] = {0.f, 0.f};
        #pragma unroll
        for (int m2 = 0; m2 < 2; ++m2) {
            #pragma unroll
            for (int i = 0; i < 2; ++i) {
                if (i < c3) {
                    const int ntg = (i == 0) ? wv : 8;
                    const int n0 = ntg * 16 + lg * 4;
                    f32x4 bv = *(const f32x4*)(b3c + n0);
                    f32x4 v = acc[m2][i] + bv;
                    if (ntg == 0) {
                        if (lg == 0) { pred[m2] = v.x; tgt[m2] = v.y; }
                    } else {
                        ushort4v zu;
                        #pragma unroll
                        for (int r = 0; r < 4; ++r) {
                            unsigned short us = f32_to_bf16_rne(v[r]);
                            float zf32 = __uint_as_float(((unsigned int)us) << 16);
                            ssq[m2] += zf32 * zf32;
                            zu[r] = us;
                        }
                        const int ch = (ntg - 1) * 2 + (lg >> 1);
                        const int kk = ch >> 2;
                        const int lane2 = (ch & 3) * 16 + l15;
                        const int e0 = (lg & 1) * 4;
                        *(ushort4v*)(zf + ((size_t)((mt0 + m2) * 4 + kk) * 64 + lane2) * 8 + e0) = zu;
                    }
                }
            }
        }
        #pragma unroll
        for (int m2 = 0; m2 < 2; ++m2) {
            float sv = ssq[m2];
            sv += __shfl_xor(sv, 16);
            sv += __shfl_xor(sv, 32);
            if (lg == 0) sred[m2][wv][l15] = sv;
        }
        __syncthreads();
        if (t < 32) {
            const int m2 = t >> 4, idx = t & 15;
            float sm = 0.f;
            #pragma unroll
            for (int w8 = 0; w8 < 8; ++w8) sm += sred[m2][w8][idx];
            sq[(mt0 + m2) * 16 + idx] = sm;
        }
        if (wv == 0 && lg == 0) {
            #pragma unroll
            for (int m2 = 0; m2 < 2; ++m2) {
                float d = pred[m2] - tgt[m2];
                alpha[(mt0 + m2) * 16 + l15] = d * d;
            }
        }
    }
}

// ---------------- K1b: threshold pre-pass (= split 0 of k_pairs; writes part[0]) ----------------
__global__ __launch_bounds__(256, 4) void k_thr(
    const unsigned short* __restrict__ zf, const float* __restrict__ sq,
    float* __restrict__ thrA, float* __restrict__ part)
{
    __shared__ float buf[4][64][BCAP];
    __shared__ float sqs[512];
    const int t = threadIdx.x;
    const int lane = t & 63, wv = t >> 6;
    const int qt16 = blockIdx.x * 4 + wv;
    const int l15 = lane & 15, lg = lane >> 4;

    sqs[t] = sq[t];
    sqs[t + 256] = sq[t + 256];
    __syncthreads();

    float* bp = &buf[wv][lane][0];
    const int qid = qt16 * 16 + l15;
    bf16x8 bq[4];
    {
        const unsigned short* qp = zf + ((size_t)qt16 * 256 + lane) * 8;
        #pragma unroll
        for (int kk = 0; kk < 4; ++kk) bq[kk] = *(const bf16x8*)(qp + kk * 512);
    }

    float vals[K2];
    #pragma unroll
    for (int i = 0; i < K2; ++i) vals[i] = BIGF;
    float thr = BIGF;
    int cnt = 0;

    const unsigned short* zcl = zf + (size_t)lane * 8;
    bf16x8 av[4];
    #pragma unroll
    for (int kk = 0; kk < 4; ++kk) av[kk] = *(const bf16x8*)(zcl + kk * 512);

    for (int tile = 0; tile < 32; ++tile) {
        f32x4 accA = {0.f, 0.f, 0.f, 0.f};
        f32x4 accB = {0.f, 0.f, 0.f, 0.f};
        accA = __builtin_amdgcn_mfma_f32_16x16x32_bf16(av[0], bq[0], accA, 0, 0, 0);
        accB = __builtin_amdgcn_mfma_f32_16x16x32_bf16(av[1], bq[1], accB, 0, 0, 0);
        accA = __builtin_amdgcn_mfma_f32_16x16x32_bf16(av[2], bq[2], accA, 0, 0, 0);
        accB = __builtin_amdgcn_mfma_f32_16x16x32_bf16(av[3], bq[3], accB, 0, 0, 0);
        if (tile < 31) {
            const unsigned short* p = zcl + (size_t)(tile + 1) * 2048;
            #pragma unroll
            for (int kk = 0; kk < 4; ++kk) av[kk] = *(const bf16x8*)(p + kk * 512);
        }
        f32x4 acc = accA + accB;
        f32x4 sqv = *(const f32x4*)(&sqs[tile * 16 + lg * 4]);
        #pragma unroll
        for (int r = 0; r < 4; ++r) {
            float v = fmaf(-2.0f, acc[r], sqv[r]);
            bp[cnt] = v;
            cnt += (int)(v <= thr);
        }
        if (__any(cnt >= TRIG)) { compactB(vals, bp, cnt); thr = vals[K2 - 1]; cnt = 0; }
    }
    compactB(vals, bp, cnt);

    float wk[K2];
    #pragma unroll
    for (int i = 0; i < K2; ++i) {
        float o = __shfl_xor(vals[K2 - 1 - i], 16);
        wk[i] = fminf(vals[i], o);
    }
    sortBitonic11(wk);
    float m1[K2];
    #pragma unroll
    for (int i = 0; i < K2; ++i) {
        float o = __shfl_xor(wk[K2 - 1 - i], 32);
        m1[i] = fminf(wk[i], o);
    }
    if (lg == 0) {
        float mx = m1[0];
        #pragma unroll
        for (int i = 1; i < K2; ++i) mx = fmaxf(mx, m1[i]);
        thrA[qid] = mx;
        float* dst = part + (size_t)qid * K2;
        #pragma unroll
        for (int i = 0; i < K2; ++i) dst[i] = m1[i];
    }
}

// ---------------- K2: pairwise + sample-thresholded top-11 (splits 1..15) ----------------
__global__ __launch_bounds__(256, 4) void k_pairs(
    const unsigned short* __restrict__ zf, const float* __restrict__ sq,
    const float* __restrict__ thrA, float* __restrict__ part)
{
    __shared__ float buf[4][2][64][BCAP];
    __shared__ float sqs[512];
    const int t = threadIdx.x;
    const int lane = t & 63;
    const int wv = t >> 6;
    const int split = 1 + (blockIdx.x % 15);
    const int qg = (blockIdx.x / 15) * 4 + wv;
    const int l15 = lane & 15, lg = lane >> 4;
    const int c0 = split * 512;

    sqs[t] = sq[c0 + t];
    sqs[t + 256] = sq[c0 + t + 256];
    __syncthreads();

    float* bp0 = &buf[wv][0][lane][0];
    float* bp1 = &buf[wv][1][lane][0];

    const int qid0 = qg * 32 + l15;
    const int qid1 = qg * 32 + 16 + l15;
    bf16x8 bq[2][4];
    {
        const unsigned short* qp0 = zf + ((size_t)(qg * 2) * 256 + lane) * 8;
        const unsigned short* qp1 = zf + ((size_t)(qg * 2 + 1) * 256 + lane) * 8;
        #pragma unroll
        for (int kk = 0; kk < 4; ++kk) {
            bq[0][kk] = *(const bf16x8*)(qp0 + kk * 512);
            bq[1][kk] = *(const bf16x8*)(qp1 + kk * 512);
        }
    }
    float thr0 = thrA[qid0];
    float thr1 = thrA[qid1];

    float vals[2][K2];
    #pragma unroll
    for (int qt = 0; qt < 2; ++qt)
        #pragma unroll
        for (int i = 0; i < K2; ++i) vals[qt][i] = BIGF;
    int cnt0 = 0, cnt1 = 0;

    const unsigned short* zcl = zf + ((size_t)(split * 32) * 256 + lane) * 8;
    bf16x8 avA[4], avB[4];
    #pragma unroll
    for (int kk = 0; kk < 4; ++kk) avA[kk] = *(const bf16x8*)(zcl + kk * 512);
    #pragma unroll
    for (int kk = 0; kk < 4; ++kk) avB[kk] = *(const bf16x8*)(zcl + 2048 + kk * 512);

    for (int tile = 0; tile < 32; tile += 2) {
        {
            f32x4 a0A = {0.f,0.f,0.f,0.f}, a0B = {0.f,0.f,0.f,0.f};
            f32x4 a1A = {0.f,0.f,0.f,0.f}, a1B = {0.f,0.f,0.f,0.f};
            a0A = __builtin_amdgcn_mfma_f32_16x16x32_bf16(avA[0], bq[0][0], a0A, 0, 0, 0);
            a1A = __builtin_amdgcn_mfma_f32_16x16x32_bf16(avA[0], bq[1][0], a1A, 0, 0, 0);
            a0B = __builtin_amdgcn_mfma_f32_16x16x32_bf16(avA[1], bq[0][1], a0B, 0, 0, 0);
            a1B = __builtin_amdgcn_mfma_f32_16x16x32_bf16(avA[1], bq[1][1], a1B, 0, 0, 0);
            a0A = __builtin_amdgcn_mfma_f32_16x16x32_bf16(avA[2], bq[0][2], a0A, 0, 0, 0);
            a1A = __builtin_amdgcn_mfma_f32_16x16x32_bf16(avA[2], bq[1][2], a1A, 0, 0, 0);
            a0B = __builtin_amdgcn_mfma_f32_16x16x32_bf16(avA[3], bq[0][3], a0B, 0, 0, 0);
            a1B = __builtin_amdgcn_mfma_f32_16x16x32_bf16(avA[3], bq[1][3], a1B, 0, 0, 0);
            if (tile + 2 < 32) {
                const unsigned short* p = zcl + (size_t)(tile + 2) * 2048;
                #pragma unroll
                for (int kk = 0; kk < 4; ++kk) avA[kk] = *(const bf16x8*)(p + kk * 512);
            }
            f32x4 acc0 = a0A + a0B;
            f32x4 acc1 = a1A + a1B;
            f32x4 sqv = *(const f32x4*)(&sqs[tile * 16 + lg * 4]);
            #pragma unroll
            for (int r = 0; r < 4; ++r) {
                float v0 = fmaf(-2.0f, acc0[r], sqv[r]);
                bp0[cnt0] = v0;
                cnt0 += (int)(v0 <= thr0);
                float v1 = fmaf(-2.0f, acc1[r], sqv[r]);
                bp1[cnt1] = v1;
                cnt1 += (int)(v1 <= thr1);
            }
            if (__any(cnt0 >= TRIG)) { compactB(vals[0], bp0, cnt0); thr0 = fminf(thr0, vals[0][K2 - 1]); cnt0 = 0; }
            if (__any(cnt1 >= TRIG)) { compactB(vals[1], bp1, cnt1); thr1 = fminf(thr1, vals[1][K2 - 1]); cnt1 = 0; }
        }
        {
            f32x4 a0A = {0.f,0.f,0.f,0.f}, a0B = {0.f,0.f,0.f,0.f};
            f32x4 a1A = {0.f,0.f,0.f,0.f}, a1B = {0.f,0.f,0.f,0.f};
            a0A = __builtin_amdgcn_mfma_f32_16x16x32_bf16(avB[0], bq[0][0], a0A, 0, 0, 0);
            a1A = __builtin_amdgcn_mfma_f32_16x16x32_bf16(avB[0], bq[1][0], a1A, 0, 0, 0);
            a0B = __builtin_amdgcn_mfma_f32_16x16x32_bf16(avB[1], bq[0][1], a0B, 0, 0, 0);
            a1B = __builtin_amdgcn_mfma_f32_16x16x32_bf16(avB[1], bq[1][1], a1B, 0, 0, 0);
            a0A = __builtin_amdgcn_mfma_f32_16x16x32_bf16(avB[2], bq[0][2], a0A, 0, 0, 0);
            a1A = __builtin_amdgcn_mfma_f32_16x16x32_bf16(avB[2], bq[1][2], a1A, 0, 0, 0);
            a0B = __builtin_amdgcn_mfma_f32_16x16x32_bf16(avB[3], bq[0][3], a0B, 0, 0, 0);
            a1B = __builtin_amdgcn_mfma_f32_16x16x32_bf16(avB[3], bq[1][3], a1B, 0, 0, 0);
            if (tile + 3 < 32) {
                const unsigned short* p = zcl + (size_t)(tile + 3) * 2048;
                #pragma unroll
                for (int kk = 0; kk < 4; ++kk) avB[kk] = *(const bf16x8*)(p + kk * 512);
            }
            f32x4 acc0 = a0A + a0B;
            f32x4 acc1 = a1A + a1B;
            f32x4 sqv = *(const f32x4*)(&sqs[(tile + 1) * 16 + lg * 4]);
            #pragma unroll
            for (int r = 0; r < 4; ++r) {
                float v0 = fmaf(-2.0f, acc0[r], sqv[r]);
                bp0[cnt0] = v0;
                cnt0 += (int)(v0 <= thr0);
                float v1 = fmaf(-2.0f, acc1[r], sqv[r]);
                bp1[cnt1] = v1;
                cnt1 += (int)(v1 <= thr1);
            }
            if (__any(cnt0 >= TRIG)) { compactB(vals[0], bp0, cnt0); thr0 = fminf(thr0, vals[0][K2 - 1]); cnt0 = 0; }
            if (__any(cnt1 >= TRIG)) { compactB(vals[1], bp1, cnt1); thr1 = fminf(thr1, vals[1][K2 - 1]); cnt1 = 0; }
        }
    }
    compactB(vals[0], bp0, cnt0);
    compactB(vals[1], bp1, cnt1);

    #pragma unroll
    for (int qt = 0; qt < 2; ++qt) {
        float wk[K2];
        #pragma unroll
        for (int i = 0; i < K2; ++i) {
            float o = __shfl_xor(vals[qt][K2 - 1 - i], 16);
            wk[i] = fminf(vals[qt][i], o);
        }
        sortBitonic11(wk);
        float m1[K2];
        #pragma unroll
        for (int i = 0; i < K2; ++i) {
            float o = __shfl_xor(wk[K2 - 1 - i], 32);
            m1[i] = fminf(wk[i], o);
        }
        if (lg == 0) {
            const int qid = (qt == 0) ? qid0 : qid1;
            float* dst = part + ((size_t)split * NROWS + qid) * K2;
            #pragma unroll
            for (int i = 0; i < K2; ++i) dst[i] = m1[i];
        }
    }
}

// ---------------- K3: merge 16 partial 11-lists (2 threads/q x 8 segs); drop min (self) ----------------
__global__ __launch_bounds__(256) void k_merge(
    const float* __restrict__ part, const float* __restrict__ sq,
    float* __restrict__ sumk, float* __restrict__ total)
{
    __shared__ float xb[128][K2 + 1];
    __shared__ float red[4];
    const int t = threadIdx.x;
    const int qi = t & 127, hf = t >> 7;
    const int q = blockIdx.x * 128 + qi;

    float vals[K2];
    #pragma unroll
    for (int i = 0; i < K2; ++i) vals[i] = BIGF;
    for (int seg = hf * 8; seg < hf * 8 + 8; ++seg) {
        const float* p = part + ((size_t)seg * NROWS + q) * K2;
        #pragma unroll
        for (int i = 0; i < K2; ++i) {
            float tv = p[i];
            if (tv < vals[K2 - 1]) insert11(vals, tv);
        }
    }
    if (hf) {
        #pragma unroll
        for (int i = 0; i < K2; ++i) xb[qi][i] = vals[i];
    }
    __syncthreads();
    float sum = 0.f;
    if (!hf) {
        #pragma unroll
        for (int i = 0; i < K2; ++i) {
            float tv = xb[qi][i];
            if (tv < vals[K2 - 1]) insert11(vals, tv);
        }
        float sqq = sq[q];
        #pragma unroll
        for (int i = 1; i < K2; ++i) {
            float raw = sqq + vals[i];
            sum += (raw > 0.f) ? sqrtf(raw) : 0.f;
        }
        sumk[q] = sum;
    }
    #pragma unroll
    for (int off = 32; off > 0; off >>= 1) sum += __shfl_down(sum, off);
    if ((t & 63) == 0) red[t >> 6] = sum;
    __syncthreads();
    if (t == 0) atomicAdd(total, red[0] + red[1] + red[2] + red[3]);
}

// ---------------- K4: finalize ----------------
__global__ __launch_bounds__(256) void k_final(
    const float* __restrict__ sumk, const float* __restrict__ alpha,
    const float* __restrict__ total, float* __restrict__ out)
{
    const int q = blockIdx.x * 256 + threadIdx.x;
    float mean = (*total) * (1.0f / NROWS);
    float m2 = mean * mean;
    float sk = sumk[q];
    float x = (sk * sk) / m2;
    float knn = EPS_CONST / (x + EPS_CONST);
    float rep = 1.0f / (sqrtf(knn) + C_CONST);
    float a = alpha[q];
    a = fminf(fmaxf(a, 1.0f), L_CONST);
    out[q] = rep * a;
}

extern "C" void kernel_launch(void* const* d_in, const int* in_sizes, int n_in,
                              void* d_out, int out_size, void* d_ws, size_t ws_size,
                              hipStream_t stream) {
    const float* s   = (const float*)d_in[0];
    const float* w1  = (const float*)d_in[1];
    const float* b1  = (const float*)d_in[2];
    const float* w2  = (const float*)d_in[3];
    const float* b2  = (const float*)d_in[4];
    const float* w3  = (const float*)d_in[5];
    const float* b3  = (const float*)d_in[6];
    const float* wt1 = (const float*)d_in[7];
    const float* bt1 = (const float*)d_in[8];
    const float* wt2 = (const float*)d_in[9];
    const float* bt2 = (const float*)d_in[10];
    const float* wt3 = (const float*)d_in[11];
    const float* bt3 = (const float*)d_in[12];
    const float* wz1 = (const float*)d_in[13];
    const float* bz1 = (const float*)d_in[14];
    const float* wz2 = (const float*)d_in[15];
    const float* bz2 = (const float*)d_in[16];
    const float* wz3 = (const float*)d_in[17];
    const float* bz3 = (const float*)d_in[18];

    char* ws = (char*)d_ws;
    unsigned short* zf  = (unsigned short*)(ws);                // 2097152
    float* sq    = (float*)(ws + 2097152);                      // 32768
    float* alpha = (float*)(ws + 2129920);                      // 32768
    float* part  = (float*)(ws + 2162688);                      // 16*8192*11*4 = 5767168
    float* sumk  = (float*)(ws + 13697024);                     // 32768
    float* total = (float*)(ws + 13729792);                     // 256
    float* thrA  = (float*)(ws + 13730048);                     // 32768
    unsigned short* w1f = (unsigned short*)(ws + 13762816);     // 786432
    unsigned short* w2f = (unsigned short*)(ws + 14549248);     // 294912
    unsigned short* w3f = (unsigned short*)(ws + 14844160);     // 110592
    float* b1c = (float*)(ws + 14954752);
    float* b2c = (float*)(ws + 14956288);
    float* b3c = (float*)(ws + 14957056);
    unsigned short* sf  = (unsigned short*)(ws + 14958592);     // 16777216

    k_prepw<<<2195, 256, 0, stream>>>(s,
                                      w1, wt1, wz1, w2, wt2, wz2, w3, wt3, wz3,
                                      b1, bt1, bz1, b2, bt2, bz2, b3, bt3, bz3,
                                      sf, w1f, w2f, w3f, b1c, b2c, b3c, total);
    k_mlp<<<256, 512, 0, stream>>>(sf, w1f, w2f, w3f, b1c, b2c, b3c, zf, sq, alpha);
    k_thr<<<128, 256, 0, stream>>>(zf, sq, thrA, part);
    k_pairs<<<960, 256, 0, stream>>>(zf, sq, thrA, part);
    k_merge<<<64, 256, 0, stream>>>(part, sq, sumk, total);
    k_final<<<32, 256, 0, stream>>>(sumk, alpha, total, (float*)d_out);
}